// Round 5
// baseline (381.785 us; speedup 1.0000x reference)
//
#include <hip/hip_runtime.h>
#include <hip/hip_fp16.h>
#include <cstdint>
#include <cstddef>

// Problem constants
#define DIMK 1024
#define NBATCH 8
#define SEQ 2048

typedef _Float16 half8 __attribute__((ext_vector_type(8)));
typedef _Float16 half4_t __attribute__((ext_vector_type(4)));
typedef float float4_t __attribute__((ext_vector_type(4)));

// async global->LDS 16B copy (gfx950). LDS dest is wave-uniform base + lane*16.
__device__ __forceinline__ void gload16(const _Float16* g, _Float16* l) {
  __builtin_amdgcn_global_load_lds((const __attribute__((address_space(1))) void*)g,
                                   (__attribute__((address_space(3))) void*)l, 16, 0, 0);
}

#define BAR() asm volatile("s_barrier" ::: "memory")
#define LGKM(n) asm volatile("s_waitcnt lgkmcnt(" #n ")" ::: "memory")
#define VMW(n) asm volatile("s_waitcnt vmcnt(" #n ")" ::: "memory")
#define PRIO1() __builtin_amdgcn_s_setprio(1)
#define PRIO0() __builtin_amdgcn_s_setprio(0)
#define SCHED0() __builtin_amdgcn_sched_barrier(0)

// ---------------------------------------------------------------------------
// 256x256-tile NT f16 GEMM core, BK=64, 512 threads = 8 waves (2M x 4N),
// v_mfma_f32_16x16x32_f16 (0-conflict read geometry).
// BALANCED-READ software pipeline: reads per phase {4,8,8,4} (x8 waves x12cyc
// = {384,768,768,384} cyc of ds-pipe) and EVERY batch is issued BEFORE its
// phase's 16-MFMA cluster (620 cyc matrix window), so the ds pipe always
// drains under MFMA cover. (Round-4 flaw: the 12-read F1 batch issued AFTER
// Ph4's MFMAs, then forced done ~100cyc later by Ph1's LGKM(4) -> ~1150
// cyc/tile uncovered ds drain; measured 5740 cyc/tile vs m201's 3300.)
//   Ph1: rd B-hi(t)[4];    LGKM(4) [F1(t) done];  Q(0,0) AfLo*BLo; stg S(t+1,Abot); BAR
//   Ph2: rd A-hi(t)[8];    LGKM(8) [B-hi done];   Q(0,1) AfLo*BHi; stg S(t+2,Atop); VMW(6); BAR
//   Ph3: rd A-lo(t+1)[8];  LGKM(8) [A-hi done];   Q(1,1) AfHi*BHi; stg S(t+2,Btop); BAR
//   Ph4: rd B-lo(t+1)[4];                         Q(1,0) AfHi*BLo; VMW(4); stg S(t+2,Bbot); BAR
// VMW(6)@Ph2 forces S(t+1,Atop/Btop) (what Ph3/Ph4 prefetch reads);
// VMW(4)@Ph4 forces S(t+1,Abot/Bbot) (what Ph1/Ph2 of t+1 read). All staged
// regions are forced >=3 phases after issue (>2000cyc > 900cyc HBM miss).
// Register roles: A-lo(t+1) reuses AfLo (dead after Ph2). B-lo(t+1) lands in
// the BHi register (dead after Ph3) -> B-register roles SWAP each tile; the
// loop is unrolled in pairs with alternating (Bf0,Bf1)/(Bf1,Bf0).
// Counted LGKMs also enforce read-before-overwrite: a region's reads are
// forced complete >=1 barrier before the staging that overwrites it.
// LDS 128 KiB: [A|B] x 2 parities; 16B-granule XOR swizzle g^(row&7); staging
// pre-swizzles the per-lane GLOBAL source so the LDS dest stays linear.
// A/B frag (16x16x32): m/n = lane&15, k = (lane>>4)*8+j.
// C/D: col = lane&15, row = (lane>>4)*4 + reg.
// ---------------------------------------------------------------------------
__device__ __forceinline__ void gemm256_core(
    const char* __restrict__ Ab, const char* __restrict__ Bb,
    const int ldA, const int ldB, const int NT, _Float16* lds,
    float4_t (&acc)[8][4])
{
  const int tid = threadIdx.x;
  const int lane = tid & 63, wave = tid >> 6;
  const int warp_m = wave >> 2, warp_n = wave & 3;
  const int srow = lane >> 3;                    // staging sub-row in 8-row chunk
  const int scb = ((lane & 7) ^ srow) << 4;      // pre-swizzled source col-byte
  const int c0 = wave * 2;                       // this wave's 1KB chunk pair
  const int fr = lane & 15, fg = lane >> 4, rsw = lane & 7;

  // loop-invariant LDS read offsets (halves)
  const int xo0 = (fg ^ rsw) << 3;
  const int xo1 = ((4 + fg) ^ rsw) << 3;
  const int aro = (warp_m * 64 + fr) * 64;           // A row base
  const int bro = 16384 + (warp_n * 32 + fr) * 64;   // B row base (B region)

  // loop-invariant staging bases
  _Float16* const sA = lds + c0 * 512;
  _Float16* const sB = lds + 16384 + c0 * 512;
  const char* const gA = Ab + (size_t)(c0 * 8 + srow) * ldA + scb;
  const char* const gB = Bb + (size_t)(c0 * 8 + srow) * ldB + scb;
  const size_t ldA8 = (size_t)ldA * 8,   ldB8 = (size_t)ldB * 8;
  const size_t ldA128 = (size_t)ldA * 128, ldB128 = (size_t)ldB * 128;

  half8 AfLo[4][2], AfHi[4][2], Bf0[2][2], Bf1[2][2];

#define STG_A(pbuf, ob_, bot) do { \
    _Float16* _lb = sA + (pbuf) + ((bot) ? 8192 : 0); \
    const char* _g = gA + ((bot) ? ldA128 : 0) + (size_t)(ob_); \
    gload16((const _Float16*)_g, _lb); \
    gload16((const _Float16*)(_g + ldA8), _lb + 512); } while (0)
#define STG_B(pbuf, ob_, bot) do { \
    _Float16* _lb = sB + (pbuf) + ((bot) ? 8192 : 0); \
    const char* _g = gB + ((bot) ? ldB128 : 0) + (size_t)(ob_); \
    gload16((const _Float16*)_g, _lb); \
    gload16((const _Float16*)(_g + ldB8), _lb + 512); } while (0)

// A fragments, row-half g (g=0: rows [0,128); g=1: +128): 8 x ds_read_b128
#define RDA(DST, pbase, g) do { \
    _Pragma("unroll") for (int m = 0; m < 4; ++m) { \
      DST[m][0] = *(const half8*)(lds + (pbase) + aro + (g) * 8192 + m * 1024 + xo0); \
      DST[m][1] = *(const half8*)(lds + (pbase) + aro + (g) * 8192 + m * 1024 + xo1); \
    } } while (0)
// B fragments, col-half g: 4 x ds_read_b128
#define RDB(DST, pbase, g) do { \
    _Pragma("unroll") for (int n = 0; n < 2; ++n) { \
      DST[n][0] = *(const half8*)(lds + (pbase) + bro + (g) * 8192 + n * 1024 + xo0); \
      DST[n][1] = *(const half8*)(lds + (pbase) + bro + (g) * 8192 + n * 1024 + xo1); \
    } } while (0)

#define QUAD(gm, gn, AF, BF) do { \
    _Pragma("unroll") for (int m = 0; m < 4; ++m) \
    _Pragma("unroll") for (int n = 0; n < 2; ++n) \
    _Pragma("unroll") for (int kk = 0; kk < 2; ++kk) \
      acc[(gm) * 4 + m][(gn) * 2 + n] = __builtin_amdgcn_mfma_f32_16x16x32_f16( \
          AF[m][kk], BF[n][kk], acc[(gm) * 4 + m][(gn) * 2 + n], 0, 0, 0); \
  } while (0)

// one steady-state K-tile; BLO/BHI alternate between Bf0/Bf1 each tile
#define TILE_STEADY(t_, BLO, BHI) do { \
    const int pb = ((t_) & 1) << 15, pbn = pb ^ 32768; \
    const int o1 = ((t_) + 1) << 7, o2 = ((t_) + 2) << 7; \
    /* Ph1 */ \
    RDB(BHI, pb, 1); \
    LGKM(4); SCHED0(); \
    PRIO1(); QUAD(0, 0, AfLo, BLO); PRIO0(); \
    STG_A(pbn, o1, 1); \
    BAR(); \
    /* Ph2 */ \
    RDA(AfHi, pb, 1); \
    LGKM(8); SCHED0(); \
    PRIO1(); QUAD(0, 1, AfLo, BHI); PRIO0(); \
    STG_A(pb, o2, 0); \
    VMW(6); \
    BAR(); \
    /* Ph3 */ \
    RDA(AfLo, pbn, 0); \
    LGKM(8); SCHED0(); \
    PRIO1(); QUAD(1, 1, AfHi, BHI); PRIO0(); \
    STG_B(pb, o2, 0); \
    BAR(); \
    /* Ph4: prefetch B-lo(t+1) into BHI (dead; becomes next tile's BLO) */ \
    RDB(BHI, pbn, 0); \
    PRIO1(); QUAD(1, 0, AfHi, BLO); PRIO0(); \
    VMW(4); \
    STG_B(pb, o2, 1); \
    BAR(); \
  } while (0)

  // prologue: tile0 complete + tile1 A-top/B-top/B-bot = 7 pairs in flight
  STG_A(0, 0, 0); STG_B(0, 0, 0); STG_B(0, 0, 1); STG_A(0, 0, 1);
  STG_A(32768, 128, 0); STG_B(32768, 128, 0); STG_B(32768, 128, 1);
  VMW(6);                    // forces tile0's 4 pairs; leaves tile1's 3
  BAR();
  RDA(AfLo, 0, 0);           // F1(0): A-lo
  RDB(Bf0, 0, 0);            //        B-lo

  // main pairs: tiles 0..NT-3  (NT is even: 16 or 32)
  for (int t = 0; t + 4 <= NT; t += 2) {
    TILE_STEADY(t, Bf0, Bf1);
    TILE_STEADY(t + 1, Bf1, Bf0);
  }
  // tile NT-2 (roles Bf0=lo, Bf1=hi): last staging is S(NT-1,Abot) in Ph1
  {
    const int pb = ((NT - 2) & 1) << 15, pbn = pb ^ 32768;
    const int o1 = (NT - 1) << 7;
    // Ph1
    RDB(Bf1, pb, 1);
    LGKM(4); SCHED0();
    PRIO1(); QUAD(0, 0, AfLo, Bf0); PRIO0();
    STG_A(pbn, o1, 1);
    BAR();
    // Ph2
    RDA(AfHi, pb, 1);
    LGKM(8); SCHED0();
    PRIO1(); QUAD(0, 1, AfLo, Bf1); PRIO0();
    VMW(4);                  // forces S(NT-1,Atop), S(NT-1,Btop)
    BAR();
    // Ph3
    RDA(AfLo, pbn, 0);
    LGKM(8); SCHED0();
    PRIO1(); QUAD(1, 1, AfHi, Bf1); PRIO0();
    BAR();
    // Ph4
    RDB(Bf1, pbn, 0);        // next tile's B-lo into Bf1
    PRIO1(); QUAD(1, 0, AfHi, Bf0); PRIO0();
    VMW(0);                  // S(NT-1,Bbot), S(NT-1,Abot) done
    BAR();
  }
  // tile NT-1 (roles Bf1=lo, Bf0=hi): fully resident, no staging/barriers
  {
    const int pb = ((NT - 1) & 1) << 15;
    RDB(Bf0, pb, 1);
    LGKM(4); SCHED0();
    QUAD(0, 0, AfLo, Bf1);
    RDA(AfHi, pb, 1);
    LGKM(8); SCHED0();
    QUAD(0, 1, AfLo, Bf0);
    LGKM(0); SCHED0();
    QUAD(1, 1, AfHi, Bf0);
    QUAD(1, 0, AfHi, Bf1);
  }
#undef STG_A
#undef STG_B
#undef RDA
#undef RDB
#undef QUAD
#undef TILE_STEADY
}

// C-tile coordinate helpers (interleaved wave sub-tiles)
#define ROW_LOCAL(mi) (warp_m * 64 + ((mi) & 3) * 16 + (((mi) >> 2) ? 128 : 0))
#define COL_LOCAL(nj) (warp_n * 32 + (((nj) & 1) ? 16 : 0) + (((nj) >> 1) ? 128 : 0))

// ---------------------------------------------------------------------------
// One-shot prep: cvt x (4194304 quads), W1 (262144), W2 (262144) to f16.
__global__ __launch_bounds__(256) void prep_kernel(const float* __restrict__ x,
                                                   const float* __restrict__ W1,
                                                   const float* __restrict__ W2,
                                                   _Float16* __restrict__ xh,
                                                   _Float16* __restrict__ Wcat) {
  int i = blockIdx.x * 256 + threadIdx.x;
  if (i < 4194304) {
    float4_t v = ((const float4_t*)x)[i];
    half4_t h; h[0]=(_Float16)v[0]; h[1]=(_Float16)v[1]; h[2]=(_Float16)v[2]; h[3]=(_Float16)v[3];
    ((half4_t*)xh)[i] = h;
  } else if (i < 4456448) {
    int j = i - 4194304;
    float4_t v = ((const float4_t*)W1)[j];
    half4_t h; h[0]=(_Float16)v[0]; h[1]=(_Float16)v[1]; h[2]=(_Float16)v[2]; h[3]=(_Float16)v[3];
    ((half4_t*)Wcat)[j] = h;
  } else if (i < 4718592) {
    int j = i - 4456448;
    float4_t v = ((const float4_t*)W2)[j];
    half4_t h; h[0]=(_Float16)v[0]; h[1]=(_Float16)v[1]; h[2]=(_Float16)v[2]; h[3]=(_Float16)v[3];
    ((half4_t*)(Wcat + 1048576))[j] = h;
  }
}

// ---------------------------------------------------------------------------
// K1: V = x@W1^T + b1 (=Q); K = x@W2^T + b2.  grid 512 = 64 bm x 8 bn.
// bn<4 -> V (+ fused V^T emission via LDS round-trip), bn>=4 -> K.
__global__ __launch_bounds__(512, 2) void gemm_vk_kernel(
    const _Float16* __restrict__ xh, const _Float16* __restrict__ Wcat,
    const float* __restrict__ b1, const float* __restrict__ b2,
    _Float16* __restrict__ Vbuf, _Float16* __restrict__ Kbuf,
    _Float16* __restrict__ Vt) {
  __shared__ _Float16 lds[65536];
  const int tid = threadIdx.x, lane = tid & 63, wave = tid >> 6;
  const int warp_m = wave >> 2, warp_n = wave & 3;
  const int fr = lane & 15, rb = (lane >> 4) * 4;
  const int flat = blockIdx.x;
  const int wg = (flat & 7) * 64 + (flat >> 3);   // XCD-contiguous
  const int bm = wg >> 3, bn = wg & 7;
  const bool isV = bn < 4;
  const float* bias = isV ? b1 : b2;
  const int ncol0 = (bn & 3) * 256;
  float bv[4];
#pragma unroll
  for (int nj = 0; nj < 4; ++nj) bv[nj] = bias[ncol0 + COL_LOCAL(nj) + fr];

  float4_t acc[8][4] = {};
  gemm256_core((const char*)(xh + (size_t)bm * 256 * DIMK),
               (const char*)(Wcat + (size_t)bn * 256 * DIMK),
               DIMK * 2, DIMK * 2, DIMK / 64, lds, acc);

  _Float16* dst = isV ? Vbuf : Kbuf;
#pragma unroll
  for (int mi = 0; mi < 8; ++mi) {
    const int row = bm * 256 + ROW_LOCAL(mi) + rb;
#pragma unroll
    for (int nj = 0; nj < 4; ++nj) {
      const int col = ncol0 + COL_LOCAL(nj) + fr;
#pragma unroll
      for (int r = 0; r < 4; ++r)
        dst[(size_t)(row + r) * DIMK + col] = (_Float16)(acc[mi][nj][r] + bv[nj]);
    }
  }
  if (isV) {
    // Fused transpose: T[d][q] in LDS (256x256 halves, granule g ^= d&31),
    // then coalesced half8 stores of Vt[b][d][q].
    __syncthreads();
#pragma unroll
    for (int mi = 0; mi < 8; ++mi) {
      const int q0 = ROW_LOCAL(mi) + rb;
#pragma unroll
      for (int nj = 0; nj < 4; ++nj) {
        const int d = COL_LOCAL(nj) + fr;
        const float bb = bv[nj];
#pragma unroll
        for (int r = 0; r < 4; ++r) {
          const int q = q0 + r;
          lds[d * 256 + ((((q >> 3) ^ d) & 31) << 3) + (q & 7)] = (_Float16)(acc[mi][nj][r] + bb);
        }
      }
    }
    __syncthreads();
    const int b = bm >> 3, qb = (bm & 7) * 256;
    const size_t vtb = ((size_t)b * DIMK + ncol0) * SEQ + qb;
#pragma unroll
    for (int i = 0; i < 16; ++i) {
      const int idx = tid + i * 512;
      const int d = idx >> 5, G = idx & 31;
      half8 v = *(const half8*)(lds + d * 256 + (((G ^ d) & 31) << 3));
      *(half8*)(Vt + vtb + (size_t)d * SEQ + G * 8) = v;
    }
  }
}

// ---------------------------------------------------------------------------
// K2: P[b,k,q] = exp(scale * K.V^T) f16, plus per-block partial row-sums ->
// rsum_part[b][bn][row] (each slot written by exactly one block, no atomics).
// grid 512 = 8b x 8bm x 8bn (one batch per XCD).
__global__ __launch_bounds__(512, 2) void gemm_scores_kernel(
    const _Float16* __restrict__ Kb, const _Float16* __restrict__ Vb,
    _Float16* __restrict__ P, float* __restrict__ rsum_part) {
  __shared__ _Float16 lds[65536];
  const int tid = threadIdx.x, lane = tid & 63, wave = tid >> 6;
  const int warp_m = wave >> 2, warp_n = wave & 3;
  const int fr = lane & 15, rb = (lane >> 4) * 4;
  const int flat = blockIdx.x;
  const int wg = (flat & 7) * 64 + (flat >> 3);
  const int b = wg >> 6, loc = wg & 63, bm = loc >> 3, bn = loc & 7;

  float4_t acc[8][4] = {};
  gemm256_core((const char*)(Kb + (size_t)(b * SEQ + bm * 256) * DIMK),
               (const char*)(Vb + (size_t)(b * SEQ + bn * 256) * DIMK),
               DIMK * 2, DIMK * 2, DIMK / 64, lds, acc);

  __syncthreads();                 // core done; reuse LDS for partial sums
  float* part = (float*)lds;       // [4 warp_n][256 rows]
  _Float16* Pb = P + (size_t)b * SEQ * SEQ;
#pragma unroll
  for (int mi = 0; mi < 8; ++mi) {
    const int rl = ROW_LOCAL(mi) + rb;
#pragma unroll
    for (int r = 0; r < 4; ++r) {
      float s = 0.f;
#pragma unroll
      for (int nj = 0; nj < 4; ++nj) {
        const int col = bn * 256 + COL_LOCAL(nj) + fr;
        const _Float16 ph = (_Float16)__expf(acc[mi][nj][r] * 0.03125f);
        Pb[(size_t)(bm * 256 + rl + r) * SEQ + col] = ph;
        s += (float)ph;
      }
      s += __shfl_xor(s, 1, 64);
      s += __shfl_xor(s, 2, 64);
      s += __shfl_xor(s, 4, 64);
      s += __shfl_xor(s, 8, 64);
      if (fr == 0) part[warp_n * 256 + rl + r] = s;
    }
  }
  __syncthreads();
  if (tid < 256) {
    const float s = part[tid] + part[256 + tid] + part[512 + tid] + part[768 + tid];
    rsum_part[((size_t)b * 8 + bn) * SEQ + bm * 256 + tid] = s;
  }
}

// ---------------------------------------------------------------------------
// K3: out[b,k,d] = (sum_q P[b,k,q]*Vt[b,d,q]) / rowsum.  rowsum combined from
// the 8 per-bn partials in the epilogue (no in-loop VALU).  grid 256.
__global__ __launch_bounds__(512, 2) void gemm_out_kernel(
    const _Float16* __restrict__ P, const _Float16* __restrict__ Vt,
    const float* __restrict__ rsum_part, float* __restrict__ out) {
  __shared__ _Float16 lds[65536];
  const int tid = threadIdx.x, lane = tid & 63, wave = tid >> 6;
  const int warp_m = wave >> 2, warp_n = wave & 3;
  const int fr = lane & 15, rb = (lane >> 4) * 4;
  const int flat = blockIdx.x;
  const int wg = (flat & 7) * 32 + (flat >> 3);
  const int b = wg >> 5, loc = wg & 31, bm = loc >> 2, bn = loc & 3;

  float4_t acc[8][4] = {};
  gemm256_core((const char*)(P + (size_t)(b * SEQ + bm * 256) * SEQ),
               (const char*)(Vt + (size_t)(b * DIMK + bn * 256) * SEQ),
               SEQ * 2, SEQ * 2, SEQ / 64, lds, acc);

  __syncthreads();                 // core done; reuse LDS for inverse sums
  float* invf = (float*)lds;       // [256 rows]
  if (tid < 256) {
    const float* rp = rsum_part + (size_t)b * 8 * SEQ + bm * 256 + tid;
    float s = 0.f;
#pragma unroll
    for (int j = 0; j < 8; ++j) s += rp[j * SEQ];
    invf[tid] = __builtin_amdgcn_rcpf(s);  // ~1ulp, fine vs 2e-3 threshold
  }
  __syncthreads();

  float* ob = out + ((size_t)b * SEQ + bm * 256) * DIMK + bn * 256;
#pragma unroll
  for (int mi = 0; mi < 8; ++mi) {
#pragma unroll
    for (int r = 0; r < 4; ++r) {
      const int row = ROW_LOCAL(mi) + rb + r;
      const float inv = invf[row];
#pragma unroll
      for (int nj = 0; nj < 4; ++nj) {
        const int col = COL_LOCAL(nj) + fr;
        ob[(size_t)row * DIMK + col] = acc[mi][nj][r] * inv;
      }
    }
  }
}

// ---------------------------------------------------------------------------
extern "C" void kernel_launch(void* const* d_in, const int* in_sizes, int n_in,
                              void* d_out, int out_size, void* d_ws, size_t ws_size,
                              hipStream_t stream) {
  const float* x  = (const float*)d_in[0];
  const float* W1 = (const float*)d_in[1];
  const float* b1 = (const float*)d_in[2];
  const float* W2 = (const float*)d_in[3];
  const float* b2 = (const float*)d_in[4];
  float* out = (float*)d_out;

  // workspace layout (bytes), proven safe (172 MB total):
  //   region0 @ 0: xh f16 [16384x1024] (33.5 MB, dead after gemm_vk),
  //                then P f16 [8][2048][2048] (67 MB) overlaid
  //   Vt   f16 [8][1024][2048] @  67108864 (33,554,432)
  //   Vbuf f16 [16384x1024]    @ 100663296 (33,554,432)
  //   Kbuf f16 [16384x1024]    @ 134217728 (33,554,432)
  //   Wcat f16 [2048x1024]     @ 167772160 ( 4,194,304; dead after gemm_vk)
  //   rsum_part f32 [8][8][2048] @ 167772160 (524,288) -- overlays dead Wcat
  char* ws = (char*)d_ws;
  _Float16* xh   = (_Float16*)(ws);
  _Float16* Pbuf = (_Float16*)(ws);
  _Float16* Vt   = (_Float16*)(ws + 67108864);
  _Float16* Vbuf = (_Float16*)(ws + 100663296);
  _Float16* Kbuf = (_Float16*)(ws + 134217728);
  _Float16* Wcat = (_Float16*)(ws + 167772160);
  float* rsum_part = (float*)(ws + 167772160);   // overlays Wcat (dead by then)

  prep_kernel<<<18432, 256, 0, stream>>>(x, W1, W2, xh, Wcat);
  gemm_vk_kernel<<<512, 512, 0, stream>>>(xh, Wcat, b1, b2, Vbuf, Kbuf, Vt);
  gemm_scores_kernel<<<512, 512, 0, stream>>>(Kbuf, Vbuf, Pbuf, rsum_part);
  gemm_out_kernel<<<256, 512, 0, stream>>>(Pbuf, Vt, rsum_part, out);
}

// Round 7
// 328.985 us; speedup vs baseline: 1.1605x; 1.1605x over previous
//
#include <hip/hip_runtime.h>
#include <hip/hip_fp16.h>
#include <cstdint>
#include <cstddef>

// Problem constants
#define DIMK 1024
#define NBATCH 8
#define SEQ 2048

typedef _Float16 half8 __attribute__((ext_vector_type(8)));
typedef _Float16 half4_t __attribute__((ext_vector_type(4)));
typedef float float4_t __attribute__((ext_vector_type(4)));

// async global->LDS 16B copy (gfx950). LDS dest is wave-uniform base + lane*16.
__device__ __forceinline__ void gload16(const _Float16* g, _Float16* l) {
  __builtin_amdgcn_global_load_lds((const __attribute__((address_space(1))) void*)g,
                                   (__attribute__((address_space(3))) void*)l, 16, 0, 0);
}

#define BAR() asm volatile("s_barrier" ::: "memory")
#define LGKM(n) asm volatile("s_waitcnt lgkmcnt(" #n ")" ::: "memory")
#define VMW(n) asm volatile("s_waitcnt vmcnt(" #n ")" ::: "memory")
#define PRIO1() __builtin_amdgcn_s_setprio(1)
#define PRIO0() __builtin_amdgcn_s_setprio(0)
#define SCHED0() __builtin_amdgcn_sched_barrier(0)

// ---------------------------------------------------------------------------
// 256x256-tile NT f16 GEMM core, BK=64, 512 threads = 8 waves (2M x 4N),
// v_mfma_f32_16x16x32_f16 (0-conflict read geometry).
// Balanced-read pipeline, SINGLE loop body (round-5's pair-unroll role swap
// spilled: +23.5MB WRITE_SIZE = 92B/thread scratch):
//   Ph1: rd B-hi(t)[4];                     Q(0,0) AfLo*Bf0; stg S(t+1,Abot); VMW(8); BAR
//   Ph2: rd A-hi(t)[8];  stg S(t+2,Atop);  LGKM(8) [B-hi];  Q(0,1) AfLo*Bf1; VMW(8); BAR
//   Ph3: rd A-lo(t+1)[8];stg S(t+2,Btop);  LGKM(8) [A-hi];  Q(1,1) AfHi*Bf1; VMW(8); BAR
//   Ph4: rd B-lo(t+1)[4]->Bf1 (dead);      Q(1,0) AfHi*Bf0; Bf0<=Bf1 copy
//        (compiler lgkm-drains; in-order DS => also forces A-lo); stg S(t+2,Bbot); VMW(8); BAR
// Every read batch issues BEFORE its phase's (or a later) MFMA cluster, so
// the shared LDS pipe (~2800cyc/tile incl. 64KB stage writes) drains under
// the 2480cyc of MFMA instead of serializing after it (round-4: 5740cyc/tile).
// The Bf0<-Bf1 copy (8 v_mov/tile) resolves the WAR on Bf0 without role-
// duplicated bodies. Uniform VMW(8) at each phase end leaves exactly the 4
// newest staged pairs outstanding => each half-tile is forced complete one
// full tile (~2400cyc > 900cyc HBM miss) after issue, and exactly one
// barrier before its first reader (cross-wave audited). LDS WAR: every
// region's reads are LGKM-forced >=1 barrier before the STG that overwrites.
// LDS 128 KiB: [A|B] x 2 parities; 16B-granule XOR swizzle g^(row&7); staging
// pre-swizzles the per-lane GLOBAL source so the LDS dest stays linear.
// A/B frag (16x16x32): m/n = lane&15, k = (lane>>4)*8+j.
// C/D: col = lane&15, row = (lane>>4)*4 + reg.
// ---------------------------------------------------------------------------
__device__ __forceinline__ void gemm256_core(
    const char* __restrict__ Ab, const char* __restrict__ Bb,
    const int ldA, const int ldB, const int NT, _Float16* lds,
    float4_t (&acc)[8][4])
{
  const int tid = threadIdx.x;
  const int lane = tid & 63, wave = tid >> 6;
  const int warp_m = wave >> 2, warp_n = wave & 3;
  const int srow = lane >> 3;                    // staging sub-row in 8-row chunk
  const int scb = ((lane & 7) ^ srow) << 4;      // pre-swizzled source col-byte
  const int c0 = wave * 2;                       // this wave's 1KB chunk pair
  const int fr = lane & 15, fg = lane >> 4, rsw = lane & 7;

  // loop-invariant LDS read offsets (halves)
  const int xo0 = (fg ^ rsw) << 3;
  const int xo1 = ((4 + fg) ^ rsw) << 3;
  const int aro = (warp_m * 64 + fr) * 64;           // A row base
  const int bro = 16384 + (warp_n * 32 + fr) * 64;   // B row base (B region)

  // loop-invariant staging bases
  _Float16* const sA = lds + c0 * 512;
  _Float16* const sB = lds + 16384 + c0 * 512;
  const char* const gA = Ab + (size_t)(c0 * 8 + srow) * ldA + scb;
  const char* const gB = Bb + (size_t)(c0 * 8 + srow) * ldB + scb;
  const size_t ldA8 = (size_t)ldA * 8,   ldB8 = (size_t)ldB * 8;
  const size_t ldA128 = (size_t)ldA * 128, ldB128 = (size_t)ldB * 128;

  half8 AfLo[4][2], AfHi[4][2], Bf0[2][2], Bf1[2][2];

#define STG_A(pbuf, ob_, bot) do { \
    _Float16* _lb = sA + (pbuf) + ((bot) ? 8192 : 0); \
    const char* _g = gA + ((bot) ? ldA128 : 0) + (size_t)(ob_); \
    gload16((const _Float16*)_g, _lb); \
    gload16((const _Float16*)(_g + ldA8), _lb + 512); } while (0)
#define STG_B(pbuf, ob_, bot) do { \
    _Float16* _lb = sB + (pbuf) + ((bot) ? 8192 : 0); \
    const char* _g = gB + ((bot) ? ldB128 : 0) + (size_t)(ob_); \
    gload16((const _Float16*)_g, _lb); \
    gload16((const _Float16*)(_g + ldB8), _lb + 512); } while (0)

// A fragments, row-half g (g=0: rows [0,128); g=1: +128): 8 x ds_read_b128
#define RDA(DST, pbase, g) do { \
    _Pragma("unroll") for (int m = 0; m < 4; ++m) { \
      DST[m][0] = *(const half8*)(lds + (pbase) + aro + (g) * 8192 + m * 1024 + xo0); \
      DST[m][1] = *(const half8*)(lds + (pbase) + aro + (g) * 8192 + m * 1024 + xo1); \
    } } while (0)
// B fragments, col-half g: 4 x ds_read_b128
#define RDB(DST, pbase, g) do { \
    _Pragma("unroll") for (int n = 0; n < 2; ++n) { \
      DST[n][0] = *(const half8*)(lds + (pbase) + bro + (g) * 8192 + n * 1024 + xo0); \
      DST[n][1] = *(const half8*)(lds + (pbase) + bro + (g) * 8192 + n * 1024 + xo1); \
    } } while (0)

#define QUAD(gm, gn, AF, BF) do { \
    _Pragma("unroll") for (int m = 0; m < 4; ++m) \
    _Pragma("unroll") for (int n = 0; n < 2; ++n) \
    _Pragma("unroll") for (int kk = 0; kk < 2; ++kk) \
      acc[(gm) * 4 + m][(gn) * 2 + n] = __builtin_amdgcn_mfma_f32_16x16x32_f16( \
          AF[m][kk], BF[n][kk], acc[(gm) * 4 + m][(gn) * 2 + n], 0, 0, 0); \
  } while (0)

#define BCOPY() do { \
    _Pragma("unroll") for (int n = 0; n < 2; ++n) \
    _Pragma("unroll") for (int k = 0; k < 2; ++k) Bf0[n][k] = Bf1[n][k]; \
  } while (0)

  // prologue: tile0 complete + tile1 A-top/B-top/B-bot = 7 pairs in flight
  STG_A(0, 0, 0); STG_B(0, 0, 0); STG_B(0, 0, 1); STG_A(0, 0, 1);
  STG_A(32768, 128, 0); STG_B(32768, 128, 0); STG_B(32768, 128, 1);
  VMW(6);                    // forces tile0's 4 pairs; leaves tile1's 3
  BAR();
  RDA(AfLo, 0, 0);           // A-lo(0)
  RDB(Bf0, 0, 0);            // B-lo(0)

  for (int t = 0; t + 2 < NT; ++t) {
    const int pb = (t & 1) << 15, pbn = pb ^ 32768;
    const int o1 = (t + 1) << 7, o2 = (t + 2) << 7;
    // Ph1: B-hi(t) | Q(0,0) | S(t+1,Abot)
    RDB(Bf1, pb, 1);
    SCHED0();
    PRIO1(); QUAD(0, 0, AfLo, Bf0); PRIO0();
    STG_A(pbn, o1, 1);
    VMW(8); BAR();
    // Ph2: A-hi(t) | S(t+2,Atop) | Q(0,1)
    RDA(AfHi, pb, 1);
    STG_A(pb, o2, 0);
    LGKM(8); SCHED0();
    PRIO1(); QUAD(0, 1, AfLo, Bf1); PRIO0();
    VMW(8); BAR();
    // Ph3: A-lo(t+1) | S(t+2,Btop) | Q(1,1)
    RDA(AfLo, pbn, 0);
    STG_B(pb, o2, 0);
    LGKM(8); SCHED0();
    PRIO1(); QUAD(1, 1, AfHi, Bf1); PRIO0();
    VMW(8); BAR();
    // Ph4: B-lo(t+1)->Bf1 (dead) | Q(1,0) | Bf0<-Bf1 | S(t+2,Bbot)
    RDB(Bf1, pbn, 0);
    SCHED0();
    PRIO1(); QUAD(1, 0, AfHi, Bf0); PRIO0();
    SCHED0();
    BCOPY();                  // compiler lgkm-waits for B-lo; in-order DS
    STG_B(pb, o2, 1);         //   completion also forces A-lo(t+1)
    VMW(8); BAR();
  }
  // tile NT-2: only S(NT-1,Abot) left to stage; tapered VMW drains
  {
    const int pb = ((NT - 2) & 1) << 15, pbn = pb ^ 32768;
    const int oL = (NT - 1) << 7;
    RDB(Bf1, pb, 1);
    SCHED0();
    PRIO1(); QUAD(0, 0, AfLo, Bf0); PRIO0();
    STG_A(pbn, oL, 1);
    VMW(8); BAR();            // forces S(NT-2,Abot)

    RDA(AfHi, pb, 1);
    LGKM(8); SCHED0();
    PRIO1(); QUAD(0, 1, AfLo, Bf1); PRIO0();
    VMW(6); BAR();            // forces S(NT-1,Atop)

    RDA(AfLo, pbn, 0);
    LGKM(8); SCHED0();
    PRIO1(); QUAD(1, 1, AfHi, Bf1); PRIO0();
    VMW(4); BAR();            // forces S(NT-1,Btop)

    RDB(Bf1, pbn, 0);
    SCHED0();
    PRIO1(); QUAD(1, 0, AfHi, Bf0); PRIO0();
    SCHED0();
    BCOPY();
    VMW(2); BAR();            // forces S(NT-1,Bbot)
  }
  // tile NT-1: fully resident after VMW(0)
  {
    const int pb = ((NT - 1) & 1) << 15;
    RDB(Bf1, pb, 1);
    SCHED0();
    PRIO1(); QUAD(0, 0, AfLo, Bf0); PRIO0();
    VMW(0); BAR();            // forces S(NT-1,Abot) before A-hi reads

    RDA(AfHi, pb, 1);
    LGKM(8); SCHED0();
    PRIO1(); QUAD(0, 1, AfLo, Bf1); PRIO0();
    LGKM(0); SCHED0();
    PRIO1(); QUAD(1, 1, AfHi, Bf1); QUAD(1, 0, AfHi, Bf0); PRIO0();
  }
#undef STG_A
#undef STG_B
#undef RDA
#undef RDB
#undef QUAD
#undef BCOPY
}

// C-tile coordinate helpers (interleaved wave sub-tiles)
#define ROW_LOCAL(mi) (warp_m * 64 + ((mi) & 3) * 16 + (((mi) >> 2) ? 128 : 0))
#define COL_LOCAL(nj) (warp_n * 32 + (((nj) & 1) ? 16 : 0) + (((nj) >> 1) ? 128 : 0))

// ---------------------------------------------------------------------------
// One-shot prep: cvt x (4194304 quads), W1 (262144), W2 (262144) to f16.
__global__ __launch_bounds__(256) void prep_kernel(const float* __restrict__ x,
                                                   const float* __restrict__ W1,
                                                   const float* __restrict__ W2,
                                                   _Float16* __restrict__ xh,
                                                   _Float16* __restrict__ Wcat) {
  int i = blockIdx.x * 256 + threadIdx.x;
  if (i < 4194304) {
    float4_t v = ((const float4_t*)x)[i];
    half4_t h; h[0]=(_Float16)v[0]; h[1]=(_Float16)v[1]; h[2]=(_Float16)v[2]; h[3]=(_Float16)v[3];
    ((half4_t*)xh)[i] = h;
  } else if (i < 4456448) {
    int j = i - 4194304;
    float4_t v = ((const float4_t*)W1)[j];
    half4_t h; h[0]=(_Float16)v[0]; h[1]=(_Float16)v[1]; h[2]=(_Float16)v[2]; h[3]=(_Float16)v[3];
    ((half4_t*)Wcat)[j] = h;
  } else if (i < 4718592) {
    int j = i - 4456448;
    float4_t v = ((const float4_t*)W2)[j];
    half4_t h; h[0]=(_Float16)v[0]; h[1]=(_Float16)v[1]; h[2]=(_Float16)v[2]; h[3]=(_Float16)v[3];
    ((half4_t*)(Wcat + 1048576))[j] = h;
  }
}

// ---------------------------------------------------------------------------
// K1: V = x@W1^T + b1 (=Q); K = x@W2^T + b2.  grid 512 = 64 bm x 8 bn.
// bn<4 -> V (+ fused V^T emission via LDS round-trip), bn>=4 -> K.
__global__ __launch_bounds__(512, 2) void gemm_vk_kernel(
    const _Float16* __restrict__ xh, const _Float16* __restrict__ Wcat,
    const float* __restrict__ b1, const float* __restrict__ b2,
    _Float16* __restrict__ Vbuf, _Float16* __restrict__ Kbuf,
    _Float16* __restrict__ Vt) {
  __shared__ _Float16 lds[65536];
  const int tid = threadIdx.x, lane = tid & 63, wave = tid >> 6;
  const int warp_m = wave >> 2, warp_n = wave & 3;
  const int fr = lane & 15, rb = (lane >> 4) * 4;
  const int flat = blockIdx.x;
  const int wg = (flat & 7) * 64 + (flat >> 3);   // XCD-contiguous
  const int bm = wg >> 3, bn = wg & 7;
  const bool isV = bn < 4;
  const float* bias = isV ? b1 : b2;
  const int ncol0 = (bn & 3) * 256;
  float bv[4];
#pragma unroll
  for (int nj = 0; nj < 4; ++nj) bv[nj] = bias[ncol0 + COL_LOCAL(nj) + fr];

  float4_t acc[8][4] = {};
  gemm256_core((const char*)(xh + (size_t)bm * 256 * DIMK),
               (const char*)(Wcat + (size_t)bn * 256 * DIMK),
               DIMK * 2, DIMK * 2, DIMK / 64, lds, acc);

  _Float16* dst = isV ? Vbuf : Kbuf;
#pragma unroll
  for (int mi = 0; mi < 8; ++mi) {
    const int row = bm * 256 + ROW_LOCAL(mi) + rb;
#pragma unroll
    for (int nj = 0; nj < 4; ++nj) {
      const int col = ncol0 + COL_LOCAL(nj) + fr;
#pragma unroll
      for (int r = 0; r < 4; ++r)
        dst[(size_t)(row + r) * DIMK + col] = (_Float16)(acc[mi][nj][r] + bv[nj]);
    }
  }
  if (isV) {
    // Fused transpose: T[d][q] in LDS (256x256 halves, granule g ^= d&31),
    // then coalesced half8 stores of Vt[b][d][q].
    __syncthreads();
#pragma unroll
    for (int mi = 0; mi < 8; ++mi) {
      const int q0 = ROW_LOCAL(mi) + rb;
#pragma unroll
      for (int nj = 0; nj < 4; ++nj) {
        const int d = COL_LOCAL(nj) + fr;
        const float bb = bv[nj];
#pragma unroll
        for (int r = 0; r < 4; ++r) {
          const int q = q0 + r;
          lds[d * 256 + ((((q >> 3) ^ d) & 31) << 3) + (q & 7)] = (_Float16)(acc[mi][nj][r] + bb);
        }
      }
    }
    __syncthreads();
    const int b = bm >> 3, qb = (bm & 7) * 256;
    const size_t vtb = ((size_t)b * DIMK + ncol0) * SEQ + qb;
#pragma unroll
    for (int i = 0; i < 16; ++i) {
      const int idx = tid + i * 512;
      const int d = idx >> 5, G = idx & 31;
      half8 v = *(const half8*)(lds + d * 256 + (((G ^ d) & 31) << 3));
      *(half8*)(Vt + vtb + (size_t)d * SEQ + G * 8) = v;
    }
  }
}

// ---------------------------------------------------------------------------
// K2: P[b,k,q] = exp(scale * K.V^T) f16, plus per-block partial row-sums ->
// rsum_part[b][bn][row] (each slot written by exactly one block, no atomics).
// grid 512 = 8b x 8bm x 8bn (one batch per XCD).
__global__ __launch_bounds__(512, 2) void gemm_scores_kernel(
    const _Float16* __restrict__ Kb, const _Float16* __restrict__ Vb,
    _Float16* __restrict__ P, float* __restrict__ rsum_part) {
  __shared__ _Float16 lds[65536];
  const int tid = threadIdx.x, lane = tid & 63, wave = tid >> 6;
  const int warp_m = wave >> 2, warp_n = wave & 3;
  const int fr = lane & 15, rb = (lane >> 4) * 4;
  const int flat = blockIdx.x;
  const int wg = (flat & 7) * 64 + (flat >> 3);
  const int b = wg >> 6, loc = wg & 63, bm = loc >> 3, bn = loc & 7;

  float4_t acc[8][4] = {};
  gemm256_core((const char*)(Kb + (size_t)(b * SEQ + bm * 256) * DIMK),
               (const char*)(Vb + (size_t)(b * SEQ + bn * 256) * DIMK),
               DIMK * 2, DIMK * 2, DIMK / 64, lds, acc);

  __syncthreads();                 // core done; reuse LDS for partial sums
  float* part = (float*)lds;       // [4 warp_n][256 rows]
  _Float16* Pb = P + (size_t)b * SEQ * SEQ;
#pragma unroll
  for (int mi = 0; mi < 8; ++mi) {
    const int rl = ROW_LOCAL(mi) + rb;
#pragma unroll
    for (int r = 0; r < 4; ++r) {
      float s = 0.f;
#pragma unroll
      for (int nj = 0; nj < 4; ++nj) {
        const int col = bn * 256 + COL_LOCAL(nj) + fr;
        const _Float16 ph = (_Float16)__expf(acc[mi][nj][r] * 0.03125f);
        Pb[(size_t)(bm * 256 + rl + r) * SEQ + col] = ph;
        s += (float)ph;
      }
      s += __shfl_xor(s, 1, 64);
      s += __shfl_xor(s, 2, 64);
      s += __shfl_xor(s, 4, 64);
      s += __shfl_xor(s, 8, 64);
      if (fr == 0) part[warp_n * 256 + rl + r] = s;
    }
  }
  __syncthreads();
  if (tid < 256) {
    const float s = part[tid] + part[256 + tid] + part[512 + tid] + part[768 + tid];
    rsum_part[((size_t)b * 8 + bn) * SEQ + bm * 256 + tid] = s;
  }
}

// ---------------------------------------------------------------------------
// K3: out[b,k,d] = (sum_q P[b,k,q]*Vt[b,d,q]) / rowsum.  rowsum combined from
// the 8 per-bn partials in the epilogue (no in-loop VALU).  grid 256.
__global__ __launch_bounds__(512, 2) void gemm_out_kernel(
    const _Float16* __restrict__ P, const _Float16* __restrict__ Vt,
    const float* __restrict__ rsum_part, float* __restrict__ out) {
  __shared__ _Float16 lds[65536];
  const int tid = threadIdx.x, lane = tid & 63, wave = tid >> 6;
  const int warp_m = wave >> 2, warp_n = wave & 3;
  const int fr = lane & 15, rb = (lane >> 4) * 4;
  const int flat = blockIdx.x;
  const int wg = (flat & 7) * 32 + (flat >> 3);
  const int b = wg >> 5, loc = wg & 31, bm = loc >> 2, bn = loc & 3;

  float4_t acc[8][4] = {};
  gemm256_core((const char*)(P + (size_t)(b * SEQ + bm * 256) * SEQ),
               (const char*)(Vt + (size_t)(b * DIMK + bn * 256) * SEQ),
               SEQ * 2, SEQ * 2, SEQ / 64, lds, acc);

  __syncthreads();                 // core done; reuse LDS for inverse sums
  float* invf = (float*)lds;       // [256 rows]
  if (tid < 256) {
    const float* rp = rsum_part + (size_t)b * 8 * SEQ + bm * 256 + tid;
    float s = 0.f;
#pragma unroll
    for (int j = 0; j < 8; ++j) s += rp[j * SEQ];
    invf[tid] = __builtin_amdgcn_rcpf(s);  // ~1ulp, fine vs 2e-3 threshold
  }
  __syncthreads();

  float* ob = out + ((size_t)b * SEQ + bm * 256) * DIMK + bn * 256;
#pragma unroll
  for (int mi = 0; mi < 8; ++mi) {
#pragma unroll
    for (int r = 0; r < 4; ++r) {
      const int row = ROW_LOCAL(mi) + rb + r;
      const float inv = invf[row];
#pragma unroll
      for (int nj = 0; nj < 4; ++nj) {
        const int col = COL_LOCAL(nj) + fr;
        ob[(size_t)row * DIMK + col] = acc[mi][nj][r] * inv;
      }
    }
  }
}

// ---------------------------------------------------------------------------
extern "C" void kernel_launch(void* const* d_in, const int* in_sizes, int n_in,
                              void* d_out, int out_size, void* d_ws, size_t ws_size,
                              hipStream_t stream) {
  const float* x  = (const float*)d_in[0];
  const float* W1 = (const float*)d_in[1];
  const float* b1 = (const float*)d_in[2];
  const float* W2 = (const float*)d_in[3];
  const float* b2 = (const float*)d_in[4];
  float* out = (float*)d_out;

  // workspace layout (bytes), proven safe (172 MB total):
  //   region0 @ 0: xh f16 [16384x1024] (33.5 MB, dead after gemm_vk),
  //                then P f16 [8][2048][2048] (67 MB) overlaid
  //   Vt   f16 [8][1024][2048] @  67108864 (33,554,432)
  //   Vbuf f16 [16384x1024]    @ 100663296 (33,554,432)
  //   Kbuf f16 [16384x1024]    @ 134217728 (33,554,432)
  //   Wcat f16 [2048x1024]     @ 167772160 ( 4,194,304; dead after gemm_vk)
  //   rsum_part f32 [8][8][2048] @ 167772160 (524,288) -- overlays dead Wcat
  char* ws = (char*)d_ws;
  _Float16* xh   = (_Float16*)(ws);
  _Float16* Pbuf = (_Float16*)(ws);
  _Float16* Vt   = (_Float16*)(ws + 67108864);
  _Float16* Vbuf = (_Float16*)(ws + 100663296);
  _Float16* Kbuf = (_Float16*)(ws + 134217728);
  _Float16* Wcat = (_Float16*)(ws + 167772160);
  float* rsum_part = (float*)(ws + 167772160);   // overlays Wcat (dead by then)

  prep_kernel<<<18432, 256, 0, stream>>>(x, W1, W2, xh, Wcat);
  gemm_vk_kernel<<<512, 512, 0, stream>>>(xh, Wcat, b1, b2, Vbuf, Kbuf, Vt);
  gemm_scores_kernel<<<512, 512, 0, stream>>>(Kbuf, Vbuf, Pbuf, rsum_part);
  gemm_out_kernel<<<256, 512, 0, stream>>>(Pbuf, Vt, rsum_part, out);
}